// Round 3
// baseline (1931.677 us; speedup 1.0000x reference)
//
#include <hip/hip_runtime.h>

typedef unsigned short u16;
typedef unsigned int u32;
typedef __attribute__((ext_vector_type(4))) float f32x4;

#define DEV __device__ __forceinline__

DEV float fsilu(float v){ return v / (1.f + __expf(-v)); }

constexpr int Bn = 32, Cin = 64, H = 56, Wd = 56, HID = 384, CO = 64;
constexpr int HW = H * Wd;            // 3136
constexpr float EPS = 1e-5f;

// ---------------------------------------------------------------------------
// K1: expand 3x3 conv (64 -> 384) + BN1 + SiLU -> h (f32, chunk-local)
// grid (6 ocg, 56 y, bc b), block 256.
// Thread: 2 px x 8 oc register tile. LDS: 3 input rows x 64 ic (f32) +
// 8-ic weight chunk (f32). 67.6 KB -> 2 blocks/CU.
// ---------------------------------------------------------------------------
__global__ __launch_bounds__(256, 2) void k_expand(
    const float* __restrict__ x, const float* __restrict__ w,
    const float* __restrict__ g1, const float* __restrict__ b1,
    const float* __restrict__ m1, const float* __restrict__ v1,
    float* __restrict__ h, int b0)
{
  __shared__ float sx[3 * 64 * 64];   // [dy][ic][xi], xi = x+1, 49.2 KB
  __shared__ float sw[8 * 9 * 64];    // [icL*9+tap][oc], 18.4 KB
  const int tid = threadIdx.x;
  const int ocg = blockIdx.x, y = blockIdx.y, b = blockIdx.z;
  const int gb = b0 + b;

  for (int l = tid; l < 3 * 64 * 64; l += 256) {
    int xi = l & 63, ic = (l >> 6) & 63, dy = l >> 12;
    int yy = y + dy - 1, xx = xi - 1;
    float v = 0.f;
    if (yy >= 0 && yy < H && xx >= 0 && xx < Wd)
      v = x[((gb * Cin + ic) * H + yy) * Wd + xx];
    sx[l] = v;
  }

  const int pp = tid & 31, ocs = tid >> 5;
  const int px0 = (pp < 28) ? (pp * 2) : 54;   // idle lanes clamped in-bounds
  float acc[16];
  #pragma unroll
  for (int i = 0; i < 16; ++i) acc[i] = 0.f;

  for (int ch = 0; ch < 8; ++ch) {
    __syncthreads();
    // stage weights: 8 input channels x 9 taps x 64 oc
    for (int l = tid; l < 8 * 9 * 64; l += 256) {
      int oc = l & 63, it = l >> 6;   // it = icL*9 + tap, 0..71
      sw[l] = w[(ocg * 64 + oc) * 576 + ch * 72 + it];
    }
    __syncthreads();

    for (int icL = 0; icL < 8; ++icL) {
      int ic = ch * 8 + icL;
      float xv[3][4];
      #pragma unroll
      for (int dy = 0; dy < 3; ++dy) {
        int base = (dy * 64 + ic) * 64 + px0;
        xv[dy][0] = sx[base];     xv[dy][1] = sx[base + 1];
        xv[dy][2] = sx[base + 2]; xv[dy][3] = sx[base + 3];
      }
      #pragma unroll
      for (int dy = 0; dy < 3; ++dy)
      #pragma unroll
      for (int dx = 0; dx < 3; ++dx) {
        const float* wp = &sw[((icL * 9 + dy * 3 + dx) << 6) + (ocs << 3)];
        f32x4 w0 = *(const f32x4*)wp;
        f32x4 w1 = *(const f32x4*)(wp + 4);
        float wv[8] = {w0.x, w0.y, w0.z, w0.w, w1.x, w1.y, w1.z, w1.w};
        float xa = xv[dy][dx], xb = xv[dy][dx + 1];
        #pragma unroll
        for (int o = 0; o < 8; ++o) {
          acc[2 * o]     += wv[o] * xa;
          acc[2 * o + 1] += wv[o] * xb;
        }
      }
    }
  }

  if (pp < 28) {
    #pragma unroll
    for (int o = 0; o < 8; ++o) {
      int oc = ocg * 64 + ocs * 8 + o;
      float sc = g1[oc] * rsqrtf(v1[oc] + EPS);
      float sh = b1[oc] - m1[oc] * sc;
      float a0 = fsilu(acc[2 * o] * sc + sh);
      float a1 = fsilu(acc[2 * o + 1] * sc + sh);
      size_t idx = ((size_t)(b * HID + oc) * H + y) * Wd + px0;
      h[idx] = a0;
      h[idx + 1] = a1;
    }
  }
}

// ---------------------------------------------------------------------------
// K2: depthwise 3x3 + BN2 + SiLU -> d (f32), plus per-(b,c) mean for SE.
// grid (384 c, bc b), block 256. Whole 56x56 plane (+halo) in LDS.
// ---------------------------------------------------------------------------
__global__ __launch_bounds__(256) void k_dw(
    const float* __restrict__ h, const float* __restrict__ wdw,
    const float* __restrict__ g2, const float* __restrict__ b2,
    const float* __restrict__ m2, const float* __restrict__ v2,
    float* __restrict__ d, float* __restrict__ mean)
{
  __shared__ float sp[58 * 58];
  __shared__ float red[4];
  const int tid = threadIdx.x;
  const int c = blockIdx.x, b = blockIdx.y;
  const float* hp = h + (size_t)(b * HID + c) * HW;

  for (int l = tid; l < 58 * 58; l += 256) {
    int yi = l / 58, xi = l - yi * 58;
    int yy = yi - 1, xx = xi - 1;
    float v = 0.f;
    if (yy >= 0 && yy < H && xx >= 0 && xx < Wd) v = hp[yy * Wd + xx];
    sp[l] = v;
  }
  float wv[9];
  #pragma unroll
  for (int t = 0; t < 9; ++t) wv[t] = wdw[c * 9 + t];
  float sc = g2[c] * rsqrtf(v2[c] + EPS);
  float sh = b2[c] - m2[c] * sc;
  __syncthreads();

  float* dp = d + (size_t)(b * HID + c) * HW;
  float lsum = 0.f;
  for (int p = tid; p < HW; p += 256) {
    int yy = p / 56, xx = p - yy * 56;
    float s = 0.f;
    #pragma unroll
    for (int dy = 0; dy < 3; ++dy)
    #pragma unroll
    for (int dx = 0; dx < 3; ++dx)
      s += sp[(yy + dy) * 58 + xx + dx] * wv[dy * 3 + dx];
    float val = fsilu(s * sc + sh);
    dp[p] = val;
    lsum += val;
  }
  #pragma unroll
  for (int off = 32; off > 0; off >>= 1) lsum += __shfl_down(lsum, off);
  if ((tid & 63) == 0) red[tid >> 6] = lsum;
  __syncthreads();
  if (tid == 0)
    mean[b * HID + c] = (red[0] + red[1] + red[2] + red[3]) * (1.f / 3136.f);
}

// ---------------------------------------------------------------------------
// K3: SE: mean[384] -> 16 (SiLU) -> 384 (sigmoid) -> sfac. grid bc, block 256.
// ---------------------------------------------------------------------------
__global__ __launch_bounds__(256) void k_se(
    const float* __restrict__ mean, const float* __restrict__ w1,
    const float* __restrict__ w2, float* __restrict__ sfac)
{
  __shared__ float sm[HID];
  __shared__ float ps[16 * 17];
  __shared__ float s1[16];
  const int b = blockIdx.x, tid = threadIdx.x;
  for (int c = tid; c < HID; c += 256) sm[c] = mean[b * HID + c];
  __syncthreads();
  int r = tid >> 4, j = tid & 15;
  float p = 0.f;
  for (int c = j; c < HID; c += 16) p += sm[c] * w1[r * HID + c];
  ps[r * 17 + j] = p;
  __syncthreads();
  if (tid < 16) {
    float s = 0.f;
    #pragma unroll
    for (int q = 0; q < 16; ++q) s += ps[tid * 17 + q];
    s1[tid] = fsilu(s);
  }
  __syncthreads();
  for (int c = tid; c < HID; c += 256) {
    float s = 0.f;
    #pragma unroll
    for (int q = 0; q < 16; ++q) s += s1[q] * w2[c * 16 + q];
    sfac[b * HID + c] = 1.f / (1.f + __expf(-s));
  }
}

// ---------------------------------------------------------------------------
// K4: pointwise 1x1 (384 -> 64) + SE scale + BN3 + residual -> out (f32)
// grid (13 px-tiles of 256, bc b), block 256. Thread: 8 co x 8 px.
// LDS per 32-ch chunk: dt 32 KB + wl 8 KB.
// ---------------------------------------------------------------------------
__global__ __launch_bounds__(256) void k_pw(
    const float* __restrict__ d, const float* __restrict__ sfac,
    const float* __restrict__ wpw,
    const float* __restrict__ g3, const float* __restrict__ b3,
    const float* __restrict__ m3, const float* __restrict__ v3,
    const float* __restrict__ x, float* __restrict__ out, int b0)
{
  __shared__ float dt[32 * 256];   // [cL][px], SE-scaled d
  __shared__ float wl[32 * 64];    // [cL][co]
  const int tid = threadIdx.x;
  const int b = blockIdx.y, p0 = blockIdx.x * 256;
  const int gb = b0 + b;
  const int cosub = tid >> 5, pxs = tid & 31;
  float acc[8][8];
  #pragma unroll
  for (int o = 0; o < 8; ++o)
    #pragma unroll
    for (int q = 0; q < 8; ++q) acc[o][q] = 0.f;

  for (int chv = 0; chv < 12; ++chv) {
    __syncthreads();
    for (int l = tid; l < 32 * 256; l += 256) {
      int px = l & 255, cL = l >> 8;
      int c = chv * 32 + cL;
      int p = p0 + px;
      float v = 0.f;
      if (p < HW) v = d[(size_t)(b * HID + c) * HW + p] * sfac[b * HID + c];
      dt[cL * 256 + px] = v;
    }
    for (int l = tid; l < 32 * 64; l += 256) {
      int co = l & 63, cL = l >> 6;
      wl[l] = wpw[co * HID + chv * 32 + cL];
    }
    __syncthreads();
    for (int cL = 0; cL < 32; ++cL) {
      const float* wp = &wl[cL * 64 + cosub * 8];
      const float* dp = &dt[cL * 256 + pxs * 8];
      f32x4 w0 = *(const f32x4*)wp,      w1 = *(const f32x4*)(wp + 4);
      f32x4 d0 = *(const f32x4*)dp,      d1 = *(const f32x4*)(dp + 4);
      float wv[8] = {w0.x, w0.y, w0.z, w0.w, w1.x, w1.y, w1.z, w1.w};
      float dv[8] = {d0.x, d0.y, d0.z, d0.w, d1.x, d1.y, d1.z, d1.w};
      #pragma unroll
      for (int o = 0; o < 8; ++o)
        #pragma unroll
        for (int q = 0; q < 8; ++q) acc[o][q] += wv[o] * dv[q];
    }
  }

  const int p = p0 + pxs * 8;
  if (p < HW) {
    #pragma unroll
    for (int o = 0; o < 8; ++o) {
      int co = cosub * 8 + o;
      float sc = g3[co] * rsqrtf(v3[co] + EPS);
      float sh = b3[co] - m3[co] * sc;
      size_t idx = (size_t)(gb * CO + co) * HW + p;
      f32x4 x0 = *(const f32x4*)&x[idx];
      f32x4 x1 = *(const f32x4*)&x[idx + 4];
      f32x4 r0, r1;
      r0.x = acc[o][0] * sc + sh + x0.x;
      r0.y = acc[o][1] * sc + sh + x0.y;
      r0.z = acc[o][2] * sc + sh + x0.z;
      r0.w = acc[o][3] * sc + sh + x0.w;
      r1.x = acc[o][4] * sc + sh + x1.x;
      r1.y = acc[o][5] * sc + sh + x1.y;
      r1.z = acc[o][6] * sc + sh + x1.z;
      r1.w = acc[o][7] * sc + sh + x1.w;
      *(f32x4*)&out[idx] = r0;
      *(f32x4*)&out[idx + 4] = r1;
    }
  }
}

// ---------------------------------------------------------------------------
extern "C" void kernel_launch(void* const* d_in, const int* in_sizes, int n_in,
                              void* d_out, int out_size, void* d_ws, size_t ws_size,
                              hipStream_t stream)
{
  (void)in_sizes; (void)n_in; (void)out_size;
  const float* x     = (const float*)d_in[0];
  const float* w_exp = (const float*)d_in[1];
  const float* g1 = (const float*)d_in[2];
  const float* b1 = (const float*)d_in[3];
  const float* m1 = (const float*)d_in[4];
  const float* v1 = (const float*)d_in[5];
  const float* w_dw = (const float*)d_in[6];
  const float* g2 = (const float*)d_in[7];
  const float* b2 = (const float*)d_in[8];
  const float* m2 = (const float*)d_in[9];
  const float* v2 = (const float*)d_in[10];
  const float* w_se1 = (const float*)d_in[11];
  const float* w_se2 = (const float*)d_in[12];
  const float* w_pw  = (const float*)d_in[13];
  const float* g3 = (const float*)d_in[14];
  const float* b3 = (const float*)d_in[15];
  const float* m3 = (const float*)d_in[16];
  const float* v3 = (const float*)d_in[17];

  // Largest batch-chunk bc fitting ws_size:
  // need = bc*HID*HW*4 (h) + bc*HID*HW*4 (d) + bc*HID*8 (mean+sfac)
  int bc = Bn;
  while (bc > 1) {
    size_t need = (size_t)bc * HID * HW * 4 * 2 + (size_t)bc * HID * 8;
    if (need <= ws_size) break;
    bc >>= 1;
  }

  const size_t nChunk = (size_t)bc * HID * HW;
  float* h  = (float*)d_ws;
  float* dd = h + nChunk;
  float* mean = dd + nChunk;
  float* sfac = mean + (size_t)bc * HID;

  for (int b0 = 0; b0 < Bn; b0 += bc) {
    k_expand<<<dim3(6, 56, bc), 256, 0, stream>>>(x, w_exp, g1, b1, m1, v1, h, b0);
    k_dw<<<dim3(HID, bc), 256, 0, stream>>>(h, w_dw, g2, b2, m2, v2, dd, mean);
    k_se<<<bc, 256, 0, stream>>>(mean, w_se1, w_se2, sfac);
    k_pw<<<dim3(13, bc), 256, 0, stream>>>(dd, sfac, w_pw, g3, b3, m3, v3, x,
                                           (float*)d_out, b0);
  }
}

// Round 4
// 455.805 us; speedup vs baseline: 4.2379x; 4.2379x over previous
//
#include <hip/hip_runtime.h>

typedef unsigned short u16;
typedef unsigned int u32;
typedef __attribute__((ext_vector_type(4))) u32 u32x4;
typedef __attribute__((ext_vector_type(4))) float f32x4;
typedef __attribute__((ext_vector_type(8))) short s16x8;

#define DEV __device__ __forceinline__

DEV float b2f(u16 v){ union{u32 i; float f;} c; c.i = ((u32)v) << 16; return c.f; }
DEV u16 f2b(float f){
  union{float f; u32 u;} c; c.f = f;
  u32 u = c.u;
  u32 r = (u + 0x7fffu + ((u >> 16) & 1u)) >> 16;
  return (u16)r;
}
DEV float fsilu(float v){ return v / (1.f + __expf(-v)); }

constexpr int Bn = 32, Cin = 64, H = 56, Wd = 56, HID = 384, CO = 64;
constexpr int HW = H * Wd;            // 3136
constexpr float EPS = 1e-5f;

// xt geometry: per batch [58 yrow][72 slot][64 ic] bf16, yrow=y+1, slot=x+1,
// zeros at yrow 0/57 and slot 0,57..71. ic-octet o stored at position o^(slot&7).
constexpr int XROW = 72 * 64;              // shorts per yrow
constexpr int XBATCH = 58 * XROW;          // shorts per batch
// wt geometry: [octile 3][tap 9][ocl 128][64] bf16, octet o at o^(ocl&7)
constexpr int WTAP = 128 * 64;             // 8192
constexpr int WOCT = 9 * WTAP;             // 73728

// ---------------------------------------------------------------------------
// P1: pack expand weights -> wt (bf16, swizzled). one thread per element.
// ---------------------------------------------------------------------------
__global__ __launch_bounds__(256) void k_prep_w(
    const float* __restrict__ w, u16* __restrict__ wt)
{
  int t = blockIdx.x * 256 + threadIdx.x;        // < 3*73728 = 221184
  int octile = t / WOCT, r = t - octile * WOCT;
  int tap = r / WTAP, r2 = r - tap * WTAP;
  int ocl = r2 >> 6, col = r2 & 63;
  int physo = col >> 3, j = col & 7;
  int olog = physo ^ (ocl & 7);
  int ic = olog * 8 + j;
  int oc = octile * 128 + ocl;
  wt[t] = f2b(w[(oc * Cin + ic) * 9 + tap]);
}

// ---------------------------------------------------------------------------
// P2: BN1 scale/shift arrays.
// ---------------------------------------------------------------------------
__global__ __launch_bounds__(384) void k_prep_bn(
    const float* __restrict__ g1, const float* __restrict__ b1,
    const float* __restrict__ m1, const float* __restrict__ v1,
    float* __restrict__ sc1, float* __restrict__ sh1)
{
  int t = threadIdx.x;
  if (t < HID) {
    float sc = g1[t] * rsqrtf(v1[t] + EPS);
    sc1[t] = sc;
    sh1[t] = b1[t] - m1[t] * sc;
  }
}

// ---------------------------------------------------------------------------
// P3: NCHW f32 -> padded NHWC bf16 (swizzled) xt. grid (58 yrow, bc b).
// ---------------------------------------------------------------------------
__global__ __launch_bounds__(256) void k_prep_x(
    const float* __restrict__ x, u16* __restrict__ xt, int b0)
{
  __shared__ u16 sT[56 * 68];   // [xx][ic], pitch 68
  const int yrow = blockIdx.x, b = blockIdx.y;
  const int gb = b0 + b;
  const int tid = threadIdx.x;
  u16* dst = xt + (size_t)b * XBATCH + (size_t)yrow * XROW;

  if (yrow == 0 || yrow == 57) {
    u32x4 z = {0, 0, 0, 0};
    for (int i = tid; i < 576; i += 256) *(u32x4*)&dst[i * 8] = z;
    return;
  }
  const int y = yrow - 1;
  #pragma unroll
  for (int pass = 0; pass < 16; ++pass) {
    int ic = pass * 4 + (tid >> 6), xx = tid & 63;
    if (xx < 56)
      sT[xx * 68 + ic] = f2b(x[((size_t)(gb * Cin + ic) * H + y) * Wd + xx]);
  }
  __syncthreads();
  for (int t = tid; t < 576; t += 256) {
    int slot = t >> 3, physo = t & 7;
    u32x4 v = {0, 0, 0, 0};
    if (slot >= 1 && slot <= 56) {
      int olog = physo ^ (slot & 7);
      const u32* sp = (const u32*)&sT[(slot - 1) * 68 + olog * 8];
      v.x = sp[0]; v.y = sp[1]; v.z = sp[2]; v.w = sp[3];
    }
    *(u32x4*)&dst[t * 8] = v;
  }
}

// ---------------------------------------------------------------------------
// K1: expand conv as MFMA shift-GEMM. grid (3 octile, 28 ypair, bc b), 256 thr.
// Block tile: 128 oc x (2 rows x 64 slots). K = 9 taps x 64 ic.
// Waves 2x2: wave (wm,wn): oc wm*64..+63, row y0+wn. 4x4 16x16x32 frags.
// ---------------------------------------------------------------------------
__global__ __launch_bounds__(256, 2) void k_expand_mfma(
    const u16* __restrict__ xt, const u16* __restrict__ wt,
    const float* __restrict__ sc1, const float* __restrict__ sh1,
    u16* __restrict__ h)
{
  __shared__ u16 sB[4 * XROW];      // 4 input rows, 36,864 B
  __shared__ u16 sA[WTAP];          // one tap, 16,384 B
  const int tid = threadIdx.x;
  const int octile = blockIdx.x, ypair = blockIdx.y, b = blockIdx.z;
  const int y0 = ypair * 2;
  const int wave = tid >> 6, ln = tid & 63;
  const int wm = wave >> 1, wn = wave & 1;
  const int lane15 = ln & 15, quad = ln >> 4;

  // stage B: yrows y0 .. y0+3 (logical y0-1 .. y0+2)
  {
    const u16* src = xt + (size_t)b * XBATCH + (size_t)y0 * XROW;
    #pragma unroll
    for (int it = 0; it < 9; ++it) {
      int i = it * 256 + tid;
      *(u32x4*)&sB[i * 8] = *(const u32x4*)&src[i * 8];
    }
  }

  f32x4 acc[4][4];
  #pragma unroll
  for (int ms = 0; ms < 4; ++ms)
    #pragma unroll
    for (int ns = 0; ns < 4; ++ns) acc[ms][ns] = (f32x4){0.f, 0.f, 0.f, 0.f};

  const u16* wsrc = wt + (size_t)octile * WOCT;
  for (int tap = 0; tap < 9; ++tap) {
    __syncthreads();
    #pragma unroll
    for (int it = 0; it < 4; ++it) {
      int i = it * 256 + tid;
      *(u32x4*)&sA[i * 8] = *(const u32x4*)&wsrc[tap * WTAP + i * 8];
    }
    __syncthreads();
    const int dy = tap / 3, dx = tap - dy * 3;
    #pragma unroll
    for (int kk = 0; kk < 2; ++kk) {
      s16x8 af[4], bf[4];
      #pragma unroll
      for (int ms = 0; ms < 4; ++ms) {
        int ocl = wm * 64 + ms * 16 + lane15;
        int po = (kk * 4 + quad) ^ (ocl & 7);
        af[ms] = *(const s16x8*)&sA[ocl * 64 + po * 8];
      }
      #pragma unroll
      for (int ns = 0; ns < 4; ++ns) {
        int row = wn + dy;
        int slot = ns * 16 + lane15 + dx;
        int po = (kk * 4 + quad) ^ (slot & 7);
        bf[ns] = *(const s16x8*)&sB[(row * 72 + slot) * 64 + po * 8];
      }
      #pragma unroll
      for (int ms = 0; ms < 4; ++ms)
        #pragma unroll
        for (int ns = 0; ns < 4; ++ns)
          acc[ms][ns] = __builtin_amdgcn_mfma_f32_16x16x32_bf16(
              af[ms], bf[ns], acc[ms][ns], 0, 0, 0);
    }
  }

  // epilogue: BN1 + SiLU, store h bf16. oc = base + quad*4 + r, n = lane15.
  const int y = y0 + wn;
  const int xloc = lane15;   // + ns*16
  #pragma unroll
  for (int ms = 0; ms < 4; ++ms) {
    int oc0 = octile * 128 + wm * 64 + ms * 16 + quad * 4;
    f32x4 sc = *(const f32x4*)&sc1[oc0];
    f32x4 sh = *(const f32x4*)&sh1[oc0];
    float scr[4] = {sc.x, sc.y, sc.z, sc.w};
    float shr[4] = {sh.x, sh.y, sh.z, sh.w};
    #pragma unroll
    for (int ns = 0; ns < 4; ++ns) {
      int xg = ns * 16 + xloc;
      if (xg < Wd) {
        float av[4] = {acc[ms][ns].x, acc[ms][ns].y, acc[ms][ns].z, acc[ms][ns].w};
        #pragma unroll
        for (int r = 0; r < 4; ++r) {
          float val = fsilu(av[r] * scr[r] + shr[r]);
          h[((size_t)(b * HID + oc0 + r) * H + y) * Wd + xg] = f2b(val);
        }
      }
    }
  }
}

// ---------------------------------------------------------------------------
// K2: depthwise 3x3 + BN2 + SiLU -> d (bf16), plus per-(b,c) mean.
// ---------------------------------------------------------------------------
__global__ __launch_bounds__(256) void k_dw(
    const u16* __restrict__ h, const float* __restrict__ wdw,
    const float* __restrict__ g2, const float* __restrict__ b2,
    const float* __restrict__ m2, const float* __restrict__ v2,
    u16* __restrict__ d, float* __restrict__ mean)
{
  __shared__ float sp[58 * 58];
  __shared__ float red[4];
  const int tid = threadIdx.x;
  const int c = blockIdx.x, b = blockIdx.y;
  const u16* hp = h + (size_t)(b * HID + c) * HW;

  for (int l = tid; l < 58 * 58; l += 256) {
    int yi = l / 58, xi = l - yi * 58;
    int yy = yi - 1, xx = xi - 1;
    float v = 0.f;
    if (yy >= 0 && yy < H && xx >= 0 && xx < Wd) v = b2f(hp[yy * Wd + xx]);
    sp[l] = v;
  }
  float wv[9];
  #pragma unroll
  for (int t = 0; t < 9; ++t) wv[t] = wdw[c * 9 + t];
  float sc = g2[c] * rsqrtf(v2[c] + EPS);
  float sh = b2[c] - m2[c] * sc;
  __syncthreads();

  u16* dp = d + (size_t)(b * HID + c) * HW;
  float lsum = 0.f;
  for (int p = tid; p < HW; p += 256) {
    int yy = p / 56, xx = p - yy * 56;
    float s = 0.f;
    #pragma unroll
    for (int dy = 0; dy < 3; ++dy)
    #pragma unroll
    for (int dx = 0; dx < 3; ++dx)
      s += sp[(yy + dy) * 58 + xx + dx] * wv[dy * 3 + dx];
    float val = fsilu(s * sc + sh);
    dp[p] = f2b(val);
    lsum += val;
  }
  #pragma unroll
  for (int off = 32; off > 0; off >>= 1) lsum += __shfl_down(lsum, off);
  if ((tid & 63) == 0) red[tid >> 6] = lsum;
  __syncthreads();
  if (tid == 0)
    mean[b * HID + c] = (red[0] + red[1] + red[2] + red[3]) * (1.f / 3136.f);
}

// ---------------------------------------------------------------------------
// K3: SE. grid bc, block 256.
// ---------------------------------------------------------------------------
__global__ __launch_bounds__(256) void k_se(
    const float* __restrict__ mean, const float* __restrict__ w1,
    const float* __restrict__ w2, float* __restrict__ sfac)
{
  __shared__ float sm[HID];
  __shared__ float ps[16 * 17];
  __shared__ float s1[16];
  const int b = blockIdx.x, tid = threadIdx.x;
  for (int c = tid; c < HID; c += 256) sm[c] = mean[b * HID + c];
  __syncthreads();
  int r = tid >> 4, j = tid & 15;
  float p = 0.f;
  for (int c = j; c < HID; c += 16) p += sm[c] * w1[r * HID + c];
  ps[r * 17 + j] = p;
  __syncthreads();
  if (tid < 16) {
    float s = 0.f;
    #pragma unroll
    for (int q = 0; q < 16; ++q) s += ps[tid * 17 + q];
    s1[tid] = fsilu(s);
  }
  __syncthreads();
  for (int c = tid; c < HID; c += 256) {
    float s = 0.f;
    #pragma unroll
    for (int q = 0; q < 16; ++q) s += s1[q] * w2[c * 16 + q];
    sfac[b * HID + c] = 1.f / (1.f + __expf(-s));
  }
}

// ---------------------------------------------------------------------------
// K4: pointwise 1x1 (384->64) + SE scale + BN3 + residual -> out (f32).
// ---------------------------------------------------------------------------
__global__ __launch_bounds__(256) void k_pw(
    const u16* __restrict__ d, const float* __restrict__ sfac,
    const float* __restrict__ wpw,
    const float* __restrict__ g3, const float* __restrict__ b3,
    const float* __restrict__ m3, const float* __restrict__ v3,
    const float* __restrict__ x, float* __restrict__ out, int b0)
{
  __shared__ float dt[32 * 256];
  __shared__ float wl[32 * 64];
  const int tid = threadIdx.x;
  const int b = blockIdx.y, p0 = blockIdx.x * 256;
  const int gb = b0 + b;
  const int cosub = tid >> 5, pxs = tid & 31;
  float acc[8][8];
  #pragma unroll
  for (int o = 0; o < 8; ++o)
    #pragma unroll
    for (int q = 0; q < 8; ++q) acc[o][q] = 0.f;

  for (int chv = 0; chv < 12; ++chv) {
    __syncthreads();
    for (int l = tid; l < 32 * 256; l += 256) {
      int px = l & 255, cL = l >> 8;
      int c = chv * 32 + cL;
      int p = p0 + px;
      float v = 0.f;
      if (p < HW) v = b2f(d[(size_t)(b * HID + c) * HW + p]) * sfac[b * HID + c];
      dt[cL * 256 + px] = v;
    }
    for (int l = tid; l < 32 * 64; l += 256) {
      int co = l & 63, cL = l >> 6;
      wl[l] = wpw[co * HID + chv * 32 + cL];
    }
    __syncthreads();
    for (int cL = 0; cL < 32; ++cL) {
      const float* wp = &wl[cL * 64 + cosub * 8];
      const float* dp = &dt[cL * 256 + pxs * 8];
      f32x4 w0 = *(const f32x4*)wp,      w1 = *(const f32x4*)(wp + 4);
      f32x4 d0 = *(const f32x4*)dp,      d1 = *(const f32x4*)(dp + 4);
      float wv[8] = {w0.x, w0.y, w0.z, w0.w, w1.x, w1.y, w1.z, w1.w};
      float dv[8] = {d0.x, d0.y, d0.z, d0.w, d1.x, d1.y, d1.z, d1.w};
      #pragma unroll
      for (int o = 0; o < 8; ++o)
        #pragma unroll
        for (int q = 0; q < 8; ++q) acc[o][q] += wv[o] * dv[q];
    }
  }

  const int p = p0 + pxs * 8;
  if (p < HW) {
    #pragma unroll
    for (int o = 0; o < 8; ++o) {
      int co = cosub * 8 + o;
      float sc = g3[co] * rsqrtf(v3[co] + EPS);
      float sh = b3[co] - m3[co] * sc;
      size_t idx = (size_t)(gb * CO + co) * HW + p;
      f32x4 x0 = *(const f32x4*)&x[idx];
      f32x4 x1 = *(const f32x4*)&x[idx + 4];
      f32x4 r0, r1;
      r0.x = acc[o][0] * sc + sh + x0.x;
      r0.y = acc[o][1] * sc + sh + x0.y;
      r0.z = acc[o][2] * sc + sh + x0.z;
      r0.w = acc[o][3] * sc + sh + x0.w;
      r1.x = acc[o][4] * sc + sh + x1.x;
      r1.y = acc[o][5] * sc + sh + x1.y;
      r1.z = acc[o][6] * sc + sh + x1.z;
      r1.w = acc[o][7] * sc + sh + x1.w;
      *(f32x4*)&out[idx] = r0;
      *(f32x4*)&out[idx + 4] = r1;
    }
  }
}

// ---------------------------------------------------------------------------
extern "C" void kernel_launch(void* const* d_in, const int* in_sizes, int n_in,
                              void* d_out, int out_size, void* d_ws, size_t ws_size,
                              hipStream_t stream)
{
  (void)in_sizes; (void)n_in; (void)out_size;
  const float* x     = (const float*)d_in[0];
  const float* w_exp = (const float*)d_in[1];
  const float* g1 = (const float*)d_in[2];
  const float* b1 = (const float*)d_in[3];
  const float* m1 = (const float*)d_in[4];
  const float* v1 = (const float*)d_in[5];
  const float* w_dw = (const float*)d_in[6];
  const float* g2 = (const float*)d_in[7];
  const float* b2 = (const float*)d_in[8];
  const float* m2 = (const float*)d_in[9];
  const float* v2 = (const float*)d_in[10];
  const float* w_se1 = (const float*)d_in[11];
  const float* w_se2 = (const float*)d_in[12];
  const float* w_pw  = (const float*)d_in[13];
  const float* g3 = (const float*)d_in[14];
  const float* b3 = (const float*)d_in[15];
  const float* m3 = (const float*)d_in[16];
  const float* v3 = (const float*)d_in[17];

  // per-batch ws: xt 534,528 B + h 2,408,448 B + d 2,408,448 B + 3,072 B
  // fixed: wt 442,368 B + sc1/sh1 3,072 B
  const size_t perB = (size_t)XBATCH * 2 + (size_t)HID * HW * 2 * 2 + HID * 8;
  const size_t fixed = 221184 * 2 + HID * 8;
  int bc = Bn;
  while (bc > 1 && fixed + (size_t)bc * perB > ws_size) bc >>= 1;

  u16* wt = (u16*)d_ws;
  float* sc1 = (float*)(wt + 221184);
  float* sh1 = sc1 + HID;
  u16* xt = (u16*)(sh1 + HID);
  u16* h  = xt + (size_t)bc * XBATCH;
  u16* dd = h + (size_t)bc * HID * HW;
  float* mean = (float*)(dd + (size_t)bc * HID * HW);
  float* sfac = mean + (size_t)bc * HID;

  k_prep_w<<<864, 256, 0, stream>>>(w_exp, wt);
  k_prep_bn<<<1, 384, 0, stream>>>(g1, b1, m1, v1, sc1, sh1);

  for (int b0 = 0; b0 < Bn; b0 += bc) {
    k_prep_x<<<dim3(58, bc), 256, 0, stream>>>(x, xt, b0);
    k_expand_mfma<<<dim3(3, 28, bc), 256, 0, stream>>>(xt, wt, sc1, sh1, h);
    k_dw<<<dim3(HID, bc), 256, 0, stream>>>(h, w_dw, g2, b2, m2, v2, dd, mean);
    k_se<<<bc, 256, 0, stream>>>(mean, w_se1, w_se2, sfac);
    k_pw<<<dim3(13, bc), 256, 0, stream>>>(dd, sfac, w_pw, g3, b3, m3, v3, x,
                                           (float*)d_out, b0);
  }
}

// Round 5
// 327.123 us; speedup vs baseline: 5.9050x; 1.3934x over previous
//
#include <hip/hip_runtime.h>

typedef unsigned short u16;
typedef unsigned int u32;
typedef __attribute__((ext_vector_type(4))) u32 u32x4;
typedef __attribute__((ext_vector_type(4))) float f32x4;
typedef __attribute__((ext_vector_type(8))) short s16x8;

#define DEV __device__ __forceinline__

DEV float b2f(u16 v){ union{u32 i; float f;} c; c.i = ((u32)v) << 16; return c.f; }
DEV u16 f2b(float f){
  union{float f; u32 u;} c; c.f = f;
  u32 u = c.u;
  u32 r = (u + 0x7fffu + ((u >> 16) & 1u)) >> 16;
  return (u16)r;
}
DEV float fsilu(float v){ return v / (1.f + __expf(-v)); }

constexpr int Bn = 32, Cin = 64, H = 56, Wd = 56, HID = 384, CO = 64;
constexpr int HW = H * Wd;            // 3136
constexpr float EPS = 1e-5f;

// xt geometry: per batch [58 yrow][72 slot][64 ic] bf16, yrow=y+1, slot=x+1.
constexpr int XROW = 72 * 64;
constexpr int XBATCH = 58 * XROW;
// wt geometry: [octile 3][tap 9][ocl 128][64] bf16, octet o at o^(ocl&7)
constexpr int WTAP = 128 * 64;
constexpr int WOCT = 9 * WTAP;

// ---------------------------------------------------------------------------
// P1: pack expand weights -> wt (bf16, swizzled).
// ---------------------------------------------------------------------------
__global__ __launch_bounds__(256) void k_prep_w(
    const float* __restrict__ w, u16* __restrict__ wt)
{
  int t = blockIdx.x * 256 + threadIdx.x;        // < 3*73728
  int octile = t / WOCT, r = t - octile * WOCT;
  int tap = r / WTAP, r2 = r - tap * WTAP;
  int ocl = r2 >> 6, col = r2 & 63;
  int physo = col >> 3, j = col & 7;
  int olog = physo ^ (ocl & 7);
  int ic = olog * 8 + j;
  int oc = octile * 128 + ocl;
  wt[t] = f2b(w[(oc * Cin + ic) * 9 + tap]);
}

// ---------------------------------------------------------------------------
// P2: BN1 + BN3 scale/shift arrays.
// ---------------------------------------------------------------------------
__global__ __launch_bounds__(384) void k_prep_bn(
    const float* __restrict__ g1, const float* __restrict__ b1,
    const float* __restrict__ m1, const float* __restrict__ v1,
    const float* __restrict__ g3, const float* __restrict__ b3,
    const float* __restrict__ m3, const float* __restrict__ v3,
    float* __restrict__ sc1, float* __restrict__ sh1,
    float* __restrict__ sc3, float* __restrict__ sh3)
{
  int t = threadIdx.x;
  if (t < HID) {
    float sc = g1[t] * rsqrtf(v1[t] + EPS);
    sc1[t] = sc;
    sh1[t] = b1[t] - m1[t] * sc;
  }
  if (t < CO) {
    float sc = g3[t] * rsqrtf(v3[t] + EPS);
    sc3[t] = sc;
    sh3[t] = b3[t] - m3[t] * sc;
  }
}

// ---------------------------------------------------------------------------
// P3: NCHW f32 -> padded NHWC bf16 (swizzled) xt. grid (58 yrow, bc b).
// ---------------------------------------------------------------------------
__global__ __launch_bounds__(256) void k_prep_x(
    const float* __restrict__ x, u16* __restrict__ xt, int b0)
{
  __shared__ u16 sT[56 * 68];
  const int yrow = blockIdx.x, b = blockIdx.y;
  const int gb = b0 + b;
  const int tid = threadIdx.x;
  u16* dst = xt + (size_t)b * XBATCH + (size_t)yrow * XROW;

  if (yrow == 0 || yrow == 57) {
    u32x4 z = {0, 0, 0, 0};
    for (int i = tid; i < 576; i += 256) *(u32x4*)&dst[i * 8] = z;
    return;
  }
  const int y = yrow - 1;
  #pragma unroll
  for (int pass = 0; pass < 16; ++pass) {
    int ic = pass * 4 + (tid >> 6), xx = tid & 63;
    if (xx < 56)
      sT[xx * 68 + ic] = f2b(x[((size_t)(gb * Cin + ic) * H + y) * Wd + xx]);
  }
  __syncthreads();
  for (int t = tid; t < 576; t += 256) {
    int slot = t >> 3, physo = t & 7;
    u32x4 v = {0, 0, 0, 0};
    if (slot >= 1 && slot <= 56) {
      int olog = physo ^ (slot & 7);
      const u32* sp = (const u32*)&sT[(slot - 1) * 68 + olog * 8];
      v.x = sp[0]; v.y = sp[1]; v.z = sp[2]; v.w = sp[3];
    }
    *(u32x4*)&dst[t * 8] = v;
  }
}

// ---------------------------------------------------------------------------
// K1: expand conv as MFMA shift-GEMM (unchanged from round 4).
// ---------------------------------------------------------------------------
__global__ __launch_bounds__(256, 2) void k_expand_mfma(
    const u16* __restrict__ xt, const u16* __restrict__ wt,
    const float* __restrict__ sc1, const float* __restrict__ sh1,
    u16* __restrict__ h)
{
  __shared__ u16 sB[4 * XROW];
  __shared__ u16 sA[WTAP];
  const int tid = threadIdx.x;
  const int octile = blockIdx.x, ypair = blockIdx.y, b = blockIdx.z;
  const int y0 = ypair * 2;
  const int wave = tid >> 6, ln = tid & 63;
  const int wm = wave >> 1, wn = wave & 1;
  const int lane15 = ln & 15, quad = ln >> 4;

  {
    const u16* src = xt + (size_t)b * XBATCH + (size_t)y0 * XROW;
    #pragma unroll
    for (int it = 0; it < 9; ++it) {
      int i = it * 256 + tid;
      *(u32x4*)&sB[i * 8] = *(const u32x4*)&src[i * 8];
    }
  }

  f32x4 acc[4][4];
  #pragma unroll
  for (int ms = 0; ms < 4; ++ms)
    #pragma unroll
    for (int ns = 0; ns < 4; ++ns) acc[ms][ns] = (f32x4){0.f, 0.f, 0.f, 0.f};

  const u16* wsrc = wt + (size_t)octile * WOCT;
  for (int tap = 0; tap < 9; ++tap) {
    __syncthreads();
    #pragma unroll
    for (int it = 0; it < 4; ++it) {
      int i = it * 256 + tid;
      *(u32x4*)&sA[i * 8] = *(const u32x4*)&wsrc[tap * WTAP + i * 8];
    }
    __syncthreads();
    const int dy = tap / 3, dx = tap - dy * 3;
    #pragma unroll
    for (int kk = 0; kk < 2; ++kk) {
      s16x8 af[4], bf[4];
      #pragma unroll
      for (int ms = 0; ms < 4; ++ms) {
        int ocl = wm * 64 + ms * 16 + lane15;
        int po = (kk * 4 + quad) ^ (ocl & 7);
        af[ms] = *(const s16x8*)&sA[ocl * 64 + po * 8];
      }
      #pragma unroll
      for (int ns = 0; ns < 4; ++ns) {
        int row = wn + dy;
        int slot = ns * 16 + lane15 + dx;
        int po = (kk * 4 + quad) ^ (slot & 7);
        bf[ns] = *(const s16x8*)&sB[(row * 72 + slot) * 64 + po * 8];
      }
      #pragma unroll
      for (int ms = 0; ms < 4; ++ms)
        #pragma unroll
        for (int ns = 0; ns < 4; ++ns)
          acc[ms][ns] = __builtin_amdgcn_mfma_f32_16x16x32_bf16(
              af[ms], bf[ns], acc[ms][ns], 0, 0, 0);
    }
  }

  const int y = y0 + wn;
  const int xloc = lane15;
  #pragma unroll
  for (int ms = 0; ms < 4; ++ms) {
    int oc0 = octile * 128 + wm * 64 + ms * 16 + quad * 4;
    f32x4 sc = *(const f32x4*)&sc1[oc0];
    f32x4 sh = *(const f32x4*)&sh1[oc0];
    float scr[4] = {sc.x, sc.y, sc.z, sc.w};
    float shr[4] = {sh.x, sh.y, sh.z, sh.w};
    #pragma unroll
    for (int ns = 0; ns < 4; ++ns) {
      int xg = ns * 16 + xloc;
      if (xg < Wd) {
        float av[4] = {acc[ms][ns].x, acc[ms][ns].y, acc[ms][ns].z, acc[ms][ns].w};
        #pragma unroll
        for (int r = 0; r < 4; ++r) {
          float val = fsilu(av[r] * scr[r] + shr[r]);
          h[((size_t)(b * HID + oc0 + r) * H + y) * Wd + xg] = f2b(val);
        }
      }
    }
  }
}

// ---------------------------------------------------------------------------
// K2: depthwise 3x3 + BN2 + SiLU -> d (bf16), plus per-(b,c) mean (unchanged).
// ---------------------------------------------------------------------------
__global__ __launch_bounds__(256) void k_dw(
    const u16* __restrict__ h, const float* __restrict__ wdw,
    const float* __restrict__ g2, const float* __restrict__ b2,
    const float* __restrict__ m2, const float* __restrict__ v2,
    u16* __restrict__ d, float* __restrict__ mean)
{
  __shared__ float sp[58 * 58];
  __shared__ float red[4];
  const int tid = threadIdx.x;
  const int c = blockIdx.x, b = blockIdx.y;
  const u16* hp = h + (size_t)(b * HID + c) * HW;

  for (int l = tid; l < 58 * 58; l += 256) {
    int yi = l / 58, xi = l - yi * 58;
    int yy = yi - 1, xx = xi - 1;
    float v = 0.f;
    if (yy >= 0 && yy < H && xx >= 0 && xx < Wd) v = b2f(hp[yy * Wd + xx]);
    sp[l] = v;
  }
  float wv[9];
  #pragma unroll
  for (int t = 0; t < 9; ++t) wv[t] = wdw[c * 9 + t];
  float sc = g2[c] * rsqrtf(v2[c] + EPS);
  float sh = b2[c] - m2[c] * sc;
  __syncthreads();

  u16* dp = d + (size_t)(b * HID + c) * HW;
  float lsum = 0.f;
  for (int p = tid; p < HW; p += 256) {
    int yy = p / 56, xx = p - yy * 56;
    float s = 0.f;
    #pragma unroll
    for (int dy = 0; dy < 3; ++dy)
    #pragma unroll
    for (int dx = 0; dx < 3; ++dx)
      s += sp[(yy + dy) * 58 + xx + dx] * wv[dy * 3 + dx];
    float val = fsilu(s * sc + sh);
    dp[p] = f2b(val);
    lsum += val;
  }
  #pragma unroll
  for (int off = 32; off > 0; off >>= 1) lsum += __shfl_down(lsum, off);
  if ((tid & 63) == 0) red[tid >> 6] = lsum;
  __syncthreads();
  if (tid == 0)
    mean[b * HID + c] = (red[0] + red[1] + red[2] + red[3]) * (1.f / 3136.f);
}

// ---------------------------------------------------------------------------
// K3: SE (unchanged).
// ---------------------------------------------------------------------------
__global__ __launch_bounds__(256) void k_se(
    const float* __restrict__ mean, const float* __restrict__ w1,
    const float* __restrict__ w2, float* __restrict__ sfac)
{
  __shared__ float sm[HID];
  __shared__ float ps[16 * 17];
  __shared__ float s1[16];
  const int b = blockIdx.x, tid = threadIdx.x;
  for (int c = tid; c < HID; c += 256) sm[c] = mean[b * HID + c];
  __syncthreads();
  int r = tid >> 4, j = tid & 15;
  float p = 0.f;
  for (int c = j; c < HID; c += 16) p += sm[c] * w1[r * HID + c];
  ps[r * 17 + j] = p;
  __syncthreads();
  if (tid < 16) {
    float s = 0.f;
    #pragma unroll
    for (int q = 0; q < 16; ++q) s += ps[tid * 17 + q];
    s1[tid] = fsilu(s);
  }
  __syncthreads();
  for (int c = tid; c < HID; c += 256) {
    float s = 0.f;
    #pragma unroll
    for (int q = 0; q < 16; ++q) s += s1[q] * w2[c * 16 + q];
    sfac[b * HID + c] = 1.f / (1.f + __expf(-s));
  }
}

// ---------------------------------------------------------------------------
// K4: pointwise 1x1 (384->64) as MFMA GEMM. A' = wpw * sfac[b] * sc3 (folded).
// grid (25 px-tiles of 128, bc b), block 256 (4 waves).
// Wave w: px range w*32 (2 n-frags), all 64 co (4 m-frags). K = 384, 12 steps.
// ---------------------------------------------------------------------------
constexpr int PWP = 392;   // sAw pitch (elems): 392*2B=784B -> uniform banks

__global__ __launch_bounds__(256, 2) void k_pw_mfma(
    const u16* __restrict__ d, const float* __restrict__ sfac,
    const float* __restrict__ wpw,
    const float* __restrict__ sc3, const float* __restrict__ sh3,
    const float* __restrict__ x, float* __restrict__ out, int b0)
{
  __shared__ u16 sAw[64 * PWP];     // 50,176 B
  __shared__ u32 dt32[128 * 16];    // 8,192 B : [px][k-pair], pitch 16 dwords
  const int tid = threadIdx.x;
  const int b = blockIdx.y, gb = b0 + b;
  const int p0 = blockIdx.x * 128;
  const int wave = tid >> 6, ln = tid & 63;
  const int lane15 = ln & 15, quad = ln >> 4;

  // ---- stage A' once: 64 co x 384 k, bf16 = wpw * sfac[b][k] * sc3[co]
  {
    const f32x4* wp4 = (const f32x4*)wpw;
    for (int i = tid; i < 64 * 96; i += 256) {    // i indexes f32x4 chunks
      int e = i * 4;                 // flat elem = co*384 + k
      int co = e / 384, k = e - co * 384;
      f32x4 wv = wp4[i];
      float s3 = sc3[co];
      const f32x4 sf = *(const f32x4*)&sfac[b * HID + k];
      u16* dst = &sAw[co * PWP + k];
      dst[0] = f2b(wv.x * sf.x * s3);
      dst[1] = f2b(wv.y * sf.y * s3);
      dst[2] = f2b(wv.z * sf.z * s3);
      dst[3] = f2b(wv.w * sf.w * s3);
    }
  }

  f32x4 acc[4][2];
  #pragma unroll
  for (int ms = 0; ms < 4; ++ms)
    #pragma unroll
    for (int ns = 0; ns < 2; ++ns) acc[ms][ns] = (f32x4){0.f, 0.f, 0.f, 0.f};

  const int cpair = tid >> 4;        // 0..15 -> c = k0 + 2*cpair
  const int pxo = (tid & 15) * 8;    // 0,8,..,120

  for (int ks = 0; ks < 12; ++ks) {
    const int k0 = ks * 32;
    __syncthreads();
    // ---- stage B: 32 k x 128 px, transposed pack (c, c+1) -> u32
    {
      u32x4 r0 = {0,0,0,0}, r1 = {0,0,0,0};
      if (p0 + pxo + 8 <= HW) {
        int c = k0 + 2 * cpair;
        const u16* dp = d + (size_t)(b * HID + c) * HW + p0 + pxo;
        r0 = *(const u32x4*)dp;
        r1 = *(const u32x4*)(dp + HW);
      }
      u32* w0 = &dt32[(pxo + 0) * 16 + cpair];
      w0[0 * 16] = (r0.x & 0xffffu) | (r1.x << 16);
      w0[1 * 16] = (r0.x >> 16)     | (r1.x & 0xffff0000u);
      w0[2 * 16] = (r0.y & 0xffffu) | (r1.y << 16);
      w0[3 * 16] = (r0.y >> 16)     | (r1.y & 0xffff0000u);
      w0[4 * 16] = (r0.z & 0xffffu) | (r1.z << 16);
      w0[5 * 16] = (r0.z >> 16)     | (r1.z & 0xffff0000u);
      w0[6 * 16] = (r0.w & 0xffffu) | (r1.w << 16);
      w0[7 * 16] = (r0.w >> 16)     | (r1.w & 0xffff0000u);
    }
    __syncthreads();
    // ---- MFMA
    s16x8 af[4], bf[2];
    #pragma unroll
    for (int ms = 0; ms < 4; ++ms) {
      int ocl = ms * 16 + lane15;
      af[ms] = *(const s16x8*)&sAw[ocl * PWP + k0 + quad * 8];
    }
    #pragma unroll
    for (int ns = 0; ns < 2; ++ns) {
      int px = wave * 32 + ns * 16 + lane15;
      bf[ns] = *(const s16x8*)((const u16*)dt32 + px * 32 + quad * 8);
    }
    #pragma unroll
    for (int ms = 0; ms < 4; ++ms)
      #pragma unroll
      for (int ns = 0; ns < 2; ++ns)
        acc[ms][ns] = __builtin_amdgcn_mfma_f32_16x16x32_bf16(
            af[ms], bf[ns], acc[ms][ns], 0, 0, 0);
  }

  // ---- epilogue: + sh3 + residual, f32 out
  #pragma unroll
  for (int ns = 0; ns < 2; ++ns) {
    int p = p0 + wave * 32 + ns * 16 + lane15;
    if (p < HW) {
      #pragma unroll
      for (int ms = 0; ms < 4; ++ms) {
        int co0 = ms * 16 + quad * 4;
        float av[4] = {acc[ms][ns].x, acc[ms][ns].y, acc[ms][ns].z, acc[ms][ns].w};
        #pragma unroll
        for (int r = 0; r < 4; ++r) {
          size_t idx = (size_t)(gb * CO + co0 + r) * HW + p;
          out[idx] = av[r] + sh3[co0 + r] + x[idx];
        }
      }
    }
  }
}

// ---------------------------------------------------------------------------
extern "C" void kernel_launch(void* const* d_in, const int* in_sizes, int n_in,
                              void* d_out, int out_size, void* d_ws, size_t ws_size,
                              hipStream_t stream)
{
  (void)in_sizes; (void)n_in; (void)out_size;
  const float* x     = (const float*)d_in[0];
  const float* w_exp = (const float*)d_in[1];
  const float* g1 = (const float*)d_in[2];
  const float* b1 = (const float*)d_in[3];
  const float* m1 = (const float*)d_in[4];
  const float* v1 = (const float*)d_in[5];
  const float* w_dw = (const float*)d_in[6];
  const float* g2 = (const float*)d_in[7];
  const float* b2 = (const float*)d_in[8];
  const float* m2 = (const float*)d_in[9];
  const float* v2 = (const float*)d_in[10];
  const float* w_se1 = (const float*)d_in[11];
  const float* w_se2 = (const float*)d_in[12];
  const float* w_pw  = (const float*)d_in[13];
  const float* g3 = (const float*)d_in[14];
  const float* b3 = (const float*)d_in[15];
  const float* m3 = (const float*)d_in[16];
  const float* v3 = (const float*)d_in[17];

  const size_t perB = (size_t)XBATCH * 2 + (size_t)HID * HW * 2 * 2 + HID * 8;
  const size_t fixed = 221184 * 2 + HID * 8 + CO * 8;
  int bc = Bn;
  while (bc > 1 && fixed + (size_t)bc * perB > ws_size) bc >>= 1;

  u16* wt = (u16*)d_ws;
  float* sc1 = (float*)(wt + 221184);
  float* sh1 = sc1 + HID;
  float* sc3 = sh1 + HID;
  float* sh3 = sc3 + CO;
  u16* xt = (u16*)(sh3 + CO);
  u16* h  = xt + (size_t)bc * XBATCH;
  u16* dd = h + (size_t)bc * HID * HW;
  float* mean = (float*)(dd + (size_t)bc * HID * HW);
  float* sfac = mean + (size_t)bc * HID;

  k_prep_w<<<864, 256, 0, stream>>>(w_exp, wt);
  k_prep_bn<<<1, 384, 0, stream>>>(g1, b1, m1, v1, g3, b3, m3, v3,
                                   sc1, sh1, sc3, sh3);

  for (int b0 = 0; b0 < Bn; b0 += bc) {
    k_prep_x<<<dim3(58, bc), 256, 0, stream>>>(x, xt, b0);
    k_expand_mfma<<<dim3(3, 28, bc), 256, 0, stream>>>(xt, wt, sc1, sh1, h);
    k_dw<<<dim3(HID, bc), 256, 0, stream>>>(h, w_dw, g2, b2, m2, v2, dd, mean);
    k_se<<<bc, 256, 0, stream>>>(mean, w_se1, w_se2, sfac);
    k_pw_mfma<<<dim3(25, bc), 256, 0, stream>>>(dd, sfac, w_pw, sc3, sh3,
                                                x, (float*)d_out, b0);
  }
}

// Round 7
// 300.530 us; speedup vs baseline: 6.4276x; 1.0885x over previous
//
#include <hip/hip_runtime.h>

typedef unsigned short u16;
typedef unsigned int u32;
typedef __attribute__((ext_vector_type(2))) u32 u32x2;
typedef __attribute__((ext_vector_type(4))) u32 u32x4;
typedef __attribute__((ext_vector_type(4))) float f32x4;
typedef __attribute__((ext_vector_type(8))) short s16x8;

#define DEV __device__ __forceinline__

DEV float bflo(u32 u){ union{u32 i; float f;} c; c.i = u << 16; return c.f; }
DEV float bfhi(u32 u){ union{u32 i; float f;} c; c.i = u & 0xffff0000u; return c.f; }
DEV float b2f(u16 v){ union{u32 i; float f;} c; c.i = ((u32)v) << 16; return c.f; }
DEV u16 f2b(float f){
  union{float f; u32 u;} c; c.f = f;
  u32 u = c.u;
  u32 r = (u + 0x7fffu + ((u >> 16) & 1u)) >> 16;
  return (u16)r;
}
DEV float fsilu(float v){ return v / (1.f + __expf(-v)); }

// async global->LDS, 16B per lane; lds dst must be wave-uniform base
#define GLD_LDS16(gsrc, ldst)                                                  \
  __builtin_amdgcn_global_load_lds(                                            \
      (const __attribute__((address_space(1))) u32*)(gsrc),                    \
      (__attribute__((address_space(3))) u32*)(ldst), 16, 0, 0)

constexpr int Bn = 32, Cin = 64, H = 56, Wd = 56, HID = 384, CO = 64;
constexpr int HW = H * Wd;            // 3136
constexpr float EPS = 1e-5f;

constexpr int XROW = 72 * 64;         // xt: [58 yrow][72 slot][64 ic] bf16
constexpr int XBATCH = 58 * XROW;
constexpr int WTAP = 128 * 64;        // wt: [octile 3][tap 9][ocl 128][64]
constexpr int WOCT = 9 * WTAP;

// ---------------------------------------------------------------------------
// P1: pack expand weights -> wt (bf16, swizzled).
// ---------------------------------------------------------------------------
__global__ __launch_bounds__(256) void k_prep_w(
    const float* __restrict__ w, u16* __restrict__ wt)
{
  int t = blockIdx.x * 256 + threadIdx.x;        // < 3*73728
  int octile = t / WOCT, r = t - octile * WOCT;
  int tap = r / WTAP, r2 = r - tap * WTAP;
  int ocl = r2 >> 6, col = r2 & 63;
  int physo = col >> 3, j = col & 7;
  int olog = physo ^ (ocl & 7);
  int ic = olog * 8 + j;
  int oc = octile * 128 + ocl;
  wt[t] = f2b(w[(oc * Cin + ic) * 9 + tap]);
}

// ---------------------------------------------------------------------------
// P2: BN1 + BN3 scale/shift arrays.
// ---------------------------------------------------------------------------
__global__ __launch_bounds__(384) void k_prep_bn(
    const float* __restrict__ g1, const float* __restrict__ b1,
    const float* __restrict__ m1, const float* __restrict__ v1,
    const float* __restrict__ g3, const float* __restrict__ b3,
    const float* __restrict__ m3, const float* __restrict__ v3,
    float* __restrict__ sc1, float* __restrict__ sh1,
    float* __restrict__ sc3, float* __restrict__ sh3)
{
  int t = threadIdx.x;
  if (t < HID) {
    float sc = g1[t] * rsqrtf(v1[t] + EPS);
    sc1[t] = sc;
    sh1[t] = b1[t] - m1[t] * sc;
  }
  if (t < CO) {
    float sc = g3[t] * rsqrtf(v3[t] + EPS);
    sc3[t] = sc;
    sh3[t] = b3[t] - m3[t] * sc;
  }
}

// ---------------------------------------------------------------------------
// P3: NCHW f32 -> padded NHWC bf16 (swizzled) xt. grid (58 yrow, bc b).
// ---------------------------------------------------------------------------
__global__ __launch_bounds__(256) void k_prep_x(
    const float* __restrict__ x, u16* __restrict__ xt, int b0)
{
  __shared__ u16 sT[56 * 68];
  const int yrow = blockIdx.x, b = blockIdx.y;
  const int gb = b0 + b;
  const int tid = threadIdx.x;
  u16* dst = xt + (size_t)b * XBATCH + (size_t)yrow * XROW;

  if (yrow == 0 || yrow == 57) {
    u32x4 z = {0, 0, 0, 0};
    for (int i = tid; i < 576; i += 256) *(u32x4*)&dst[i * 8] = z;
    return;
  }
  const int y = yrow - 1;
  #pragma unroll
  for (int pass = 0; pass < 16; ++pass) {
    int ic = pass * 4 + (tid >> 6), xx = tid & 63;
    if (xx < 56)
      sT[xx * 68 + ic] = f2b(x[((size_t)(gb * Cin + ic) * H + y) * Wd + xx]);
  }
  __syncthreads();
  for (int t = tid; t < 576; t += 256) {
    int slot = t >> 3, physo = t & 7;
    u32x4 v = {0, 0, 0, 0};
    if (slot >= 1 && slot <= 56) {
      int olog = physo ^ (slot & 7);
      const u32* sp = (const u32*)&sT[(slot - 1) * 68 + olog * 8];
      v.x = sp[0]; v.y = sp[1]; v.z = sp[2]; v.w = sp[3];
    }
    *(u32x4*)&dst[t * 8] = v;
  }
}

// ---------------------------------------------------------------------------
// K1: expand conv MFMA shift-GEMM, async-staged + sA double-buffered.
// grid (3 octile, 28 ypair, bc b), 256 thr. 1 barrier per tap.
// ---------------------------------------------------------------------------
__global__ __launch_bounds__(256, 2) void k_expand_mfma(
    const u16* __restrict__ xt, const u16* __restrict__ wt,
    const float* __restrict__ sc1, const float* __restrict__ sh1,
    u16* __restrict__ h)
{
  __shared__ u16 sB[4 * XROW];      // 36,864 B
  __shared__ u16 sA[2 * WTAP];      // 2 x 16,384 B (double buffer)
  const int tid = threadIdx.x;
  const int octile = blockIdx.x, ypair = blockIdx.y, b = blockIdx.z;
  const int y0 = ypair * 2;
  const int wave = tid >> 6, ln = tid & 63;
  const int wm = wave >> 1, wn = wave & 1;
  const int lane15 = ln & 15, quad = ln >> 4;

  const u16* wsrc = wt + (size_t)octile * WOCT;

  // stage sB (36 KB linear) via async DMA
  {
    const u16* src = xt + (size_t)b * XBATCH + (size_t)y0 * XROW;
    #pragma unroll
    for (int it = 0; it < 9; ++it) {
      int off = (wave * 9 + it) * 512;            // u16 elems (1 KB chunks)
      GLD_LDS16(src + off + ln * 8, &sB[off]);
    }
  }
  // prefetch sA tap 0 into buf 0
  #pragma unroll
  for (int it = 0; it < 4; ++it) {
    int off = (wave * 4 + it) * 512;
    GLD_LDS16(wsrc + off + ln * 8, &sA[off]);
  }
  __syncthreads();   // drains vmcnt -> sB + sA[0] ready

  f32x4 acc[4][4];
  #pragma unroll
  for (int ms = 0; ms < 4; ++ms)
    #pragma unroll
    for (int ns = 0; ns < 4; ++ns) acc[ms][ns] = (f32x4){0.f, 0.f, 0.f, 0.f};

  for (int tap = 0; tap < 9; ++tap) {
    // async prefetch next tap into the other buffer
    if (tap < 8) {
      const u16* src = wsrc + (tap + 1) * WTAP;
      int bb = ((tap + 1) & 1) * WTAP;
      #pragma unroll
      for (int it = 0; it < 4; ++it) {
        int off = (wave * 4 + it) * 512;
        GLD_LDS16(src + off + ln * 8, &sA[bb + off]);
      }
    }
    const u16* sAb = &sA[(tap & 1) * WTAP];
    const int dy = tap / 3, dx = tap - dy * 3;
    #pragma unroll
    for (int kk = 0; kk < 2; ++kk) {
      s16x8 af[4], bf[4];
      #pragma unroll
      for (int ms = 0; ms < 4; ++ms) {
        int ocl = wm * 64 + ms * 16 + lane15;
        int po = (kk * 4 + quad) ^ (ocl & 7);
        af[ms] = *(const s16x8*)&sAb[ocl * 64 + po * 8];
      }
      #pragma unroll
      for (int ns = 0; ns < 4; ++ns) {
        int row = wn + dy;
        int slot = ns * 16 + lane15 + dx;
        int po = (kk * 4 + quad) ^ (slot & 7);
        bf[ns] = *(const s16x8*)&sB[(row * 72 + slot) * 64 + po * 8];
      }
      #pragma unroll
      for (int ms = 0; ms < 4; ++ms)
        #pragma unroll
        for (int ns = 0; ns < 4; ++ns)
          acc[ms][ns] = __builtin_amdgcn_mfma_f32_16x16x32_bf16(
              af[ms], bf[ns], acc[ms][ns], 0, 0, 0);
    }
    __syncthreads();   // one barrier per tap: reads done + prefetch landed
  }

  const int y = y0 + wn;
  #pragma unroll
  for (int ms = 0; ms < 4; ++ms) {
    int oc0 = octile * 128 + wm * 64 + ms * 16 + quad * 4;
    f32x4 sc = *(const f32x4*)&sc1[oc0];
    f32x4 sh = *(const f32x4*)&sh1[oc0];
    float scr[4] = {sc.x, sc.y, sc.z, sc.w};
    float shr[4] = {sh.x, sh.y, sh.z, sh.w};
    #pragma unroll
    for (int ns = 0; ns < 4; ++ns) {
      int xg = ns * 16 + lane15;
      if (xg < Wd) {
        float av[4] = {acc[ms][ns].x, acc[ms][ns].y, acc[ms][ns].z, acc[ms][ns].w};
        #pragma unroll
        for (int r = 0; r < 4; ++r) {
          float val = fsilu(av[r] * scr[r] + shr[r]);
          h[((size_t)(b * HID + oc0 + r) * H + y) * Wd + xg] = f2b(val);
        }
      }
    }
  }
}

// ---------------------------------------------------------------------------
// K2: depthwise 3x3 + BN2 + SiLU -> d (bf16) + per-(b,c) mean.
// Vectorized: 4 px/thread. sp layout: [58 rows][pitch 60], col = x+1.
// ---------------------------------------------------------------------------
__global__ __launch_bounds__(256) void k_dw(
    const u16* __restrict__ h, const float* __restrict__ wdw,
    const float* __restrict__ g2, const float* __restrict__ b2,
    const float* __restrict__ m2, const float* __restrict__ v2,
    u16* __restrict__ d, float* __restrict__ mean)
{
  __shared__ float sp[58 * 60];
  __shared__ float red[4];
  const int tid = threadIdx.x;
  const int c = blockIdx.x, b = blockIdx.y;
  const u16* hp = h + (size_t)(b * HID + c) * HW;

  // zero borders: rows 0,57 full; cols 0,57 of rows 1..56  (228 cells)
  if (tid < 228) {
    int r, cc;
    if (tid < 58)       { r = 0;              cc = tid; }
    else if (tid < 116) { r = 57;             cc = tid - 58; }
    else if (tid < 172) { r = tid - 116 + 1;  cc = 0; }
    else                { r = tid - 172 + 1;  cc = 57; }
    sp[r * 60 + cc] = 0.f;
  }
  // interior: 56 rows x 7 chunks of 8 px, vector global loads
  for (int t = tid; t < 56 * 7; t += 256) {
    int r = t / 7, ch = t - r * 7;
    u32x4 q = *(const u32x4*)(hp + r * Wd + ch * 8);
    float* dst = &sp[(r + 1) * 60 + 1 + ch * 8];
    u32 ua[4] = {q.x, q.y, q.z, q.w};
    #pragma unroll
    for (int j = 0; j < 4; ++j) {
      dst[2 * j]     = bflo(ua[j]);
      dst[2 * j + 1] = bfhi(ua[j]);
    }
  }
  float wv[9];
  #pragma unroll
  for (int t = 0; t < 9; ++t) wv[t] = wdw[c * 9 + t];
  float sc = g2[c] * rsqrtf(v2[c] + EPS);
  float sh = b2[c] - m2[c] * sc;
  __syncthreads();

  u16* dp = d + (size_t)(b * HID + c) * HW;
  float lsum = 0.f;
  for (int g = tid; g < 784; g += 256) {       // 784 = 56 rows x 14 groups
    int row = g / 14, gx = (g - row * 14) * 4;
    float v[3][6];
    #pragma unroll
    for (int r = 0; r < 3; ++r) {
      const float* pr = &sp[(row + r) * 60 + gx];
      f32x4 a = *(const f32x4*)pr;
      v[r][0] = a.x; v[r][1] = a.y; v[r][2] = a.z; v[r][3] = a.w;
      v[r][4] = pr[4]; v[r][5] = pr[5];
    }
    float o[4];
    #pragma unroll
    for (int j = 0; j < 4; ++j) {
      float s = 0.f;
      #pragma unroll
      for (int r = 0; r < 3; ++r)
        #pragma unroll
        for (int dx = 0; dx < 3; ++dx)
          s += v[r][j + dx] * wv[r * 3 + dx];
      o[j] = fsilu(s * sc + sh);
      lsum += o[j];
    }
    u32x2 pk;
    pk.x = (u32)f2b(o[0]) | ((u32)f2b(o[1]) << 16);
    pk.y = (u32)f2b(o[2]) | ((u32)f2b(o[3]) << 16);
    *(u32x2*)&dp[row * 56 + gx] = pk;
  }
  #pragma unroll
  for (int off = 32; off > 0; off >>= 1) lsum += __shfl_down(lsum, off);
  if ((tid & 63) == 0) red[tid >> 6] = lsum;
  __syncthreads();
  if (tid == 0)
    mean[b * HID + c] = (red[0] + red[1] + red[2] + red[3]) * (1.f / 3136.f);
}

// ---------------------------------------------------------------------------
// K3: SE (unchanged).
// ---------------------------------------------------------------------------
__global__ __launch_bounds__(256) void k_se(
    const float* __restrict__ mean, const float* __restrict__ w1,
    const float* __restrict__ w2, float* __restrict__ sfac)
{
  __shared__ float sm[HID];
  __shared__ float ps[16 * 17];
  __shared__ float s1[16];
  const int b = blockIdx.x, tid = threadIdx.x;
  for (int c = tid; c < HID; c += 256) sm[c] = mean[b * HID + c];
  __syncthreads();
  int r = tid >> 4, j = tid & 15;
  float p = 0.f;
  for (int c = j; c < HID; c += 16) p += sm[c] * w1[r * HID + c];
  ps[r * 17 + j] = p;
  __syncthreads();
  if (tid < 16) {
    float s = 0.f;
    #pragma unroll
    for (int q = 0; q < 16; ++q) s += ps[tid * 17 + q];
    s1[tid] = fsilu(s);
  }
  __syncthreads();
  for (int c = tid; c < HID; c += 256) {
    float s = 0.f;
    #pragma unroll
    for (int q = 0; q < 16; ++q) s += s1[q] * w2[c * 16 + q];
    sfac[b * HID + c] = 1.f / (1.f + __expf(-s));
  }
}

// ---------------------------------------------------------------------------
// P4: per-batch folded A' = wpw * sfac[b] * sc3, bf16 [b][co][k]. grid bc.
// ---------------------------------------------------------------------------
__global__ __launch_bounds__(256) void k_prep_a(
    const float* __restrict__ wpw, const float* __restrict__ sfac,
    const float* __restrict__ sc3, u16* __restrict__ afold)
{
  const int b = blockIdx.x, tid = threadIdx.x;
  for (int i = tid; i < 6144; i += 256) {    // f32x4 chunks of 64x384
    int e = i * 4, co = e / 384, k = e - co * 384;
    f32x4 wv = *(const f32x4*)&wpw[e];
    f32x4 sf = *(const f32x4*)&sfac[b * HID + k];
    float s3 = sc3[co];
    u32x2 pk;
    pk.x = (u32)f2b(wv.x * sf.x * s3) | ((u32)f2b(wv.y * sf.y * s3) << 16);
    pk.y = (u32)f2b(wv.z * sf.z * s3) | ((u32)f2b(wv.w * sf.w * s3) << 16);
    *(u32x2*)&afold[(size_t)b * 24576 + e] = pk;
  }
}

// ---------------------------------------------------------------------------
// K4: pointwise MFMA GEMM. grid (25 px-tiles of 128, bc b), 256 thr.
// ---------------------------------------------------------------------------
constexpr int PWP = 392;

__global__ __launch_bounds__(256, 2) void k_pw_mfma(
    const u16* __restrict__ d, const u16* __restrict__ afold,
    const float* __restrict__ sh3,
    const float* __restrict__ x, float* __restrict__ out, int b0)
{
  __shared__ u16 sAw[64 * PWP];     // 50,176 B
  __shared__ u32 dt32[128 * 16];    // 8,192 B
  const int tid = threadIdx.x;
  const int b = blockIdx.y, gb = b0 + b;
  const int p0 = blockIdx.x * 128;
  const int wave = tid >> 6, ln = tid & 63;
  const int lane15 = ln & 15, quad = ln >> 4;

  // stage A' (pure b128 copies): 24576 elems = 3072 x 8
  {
    const u16* ab = afold + (size_t)b * 24576;
    #pragma unroll
    for (int i = tid; i < 3072; i += 256) {
      int e = i * 8, co = e / 384, k = e - co * 384;
      *(u32x4*)&sAw[co * PWP + k] = *(const u32x4*)&ab[e];
    }
  }

  f32x4 acc[4][2];
  #pragma unroll
  for (int ms = 0; ms < 4; ++ms)
    #pragma unroll
    for (int ns = 0; ns < 2; ++ns) acc[ms][ns] = (f32x4){0.f, 0.f, 0.f, 0.f};

  const int cpair = tid >> 4;
  const int pxo = (tid & 15) * 8;

  for (int ks = 0; ks < 12; ++ks) {
    const int k0 = ks * 32;
    __syncthreads();
    {
      u32x4 r0 = {0,0,0,0}, r1 = {0,0,0,0};
      if (p0 + pxo + 8 <= HW) {
        int c = k0 + 2 * cpair;
        const u16* dpp = d + (size_t)(b * HID + c) * HW + p0 + pxo;
        r0 = *(const u32x4*)dpp;
        r1 = *(const u32x4*)(dpp + HW);
      }
      u32* w0 = &dt32[pxo * 16 + cpair];
      w0[0 * 16] = (r0.x & 0xffffu) | (r1.x << 16);
      w0[1 * 16] = (r0.x >> 16)     | (r1.x & 0xffff0000u);
      w0[2 * 16] = (r0.y & 0xffffu) | (r1.y << 16);
      w0[3 * 16] = (r0.y >> 16)     | (r1.y & 0xffff0000u);
      w0[4 * 16] = (r0.z & 0xffffu) | (r1.z << 16);
      w0[5 * 16] = (r0.z >> 16)     | (r1.z & 0xffff0000u);
      w0[6 * 16] = (r0.w & 0xffffu) | (r1.w << 16);
      w0[7 * 16] = (r0.w >> 16)     | (r1.w & 0xffff0000u);
    }
    __syncthreads();
    s16x8 af[4], bf[2];
    #pragma unroll
    for (int ms = 0; ms < 4; ++ms) {
      int ocl = ms * 16 + lane15;
      af[ms] = *(const s16x8*)&sAw[ocl * PWP + k0 + quad * 8];
    }
    #pragma unroll
    for (int ns = 0; ns < 2; ++ns) {
      int px = wave * 32 + ns * 16 + lane15;
      bf[ns] = *(const s16x8*)((const u16*)dt32 + px * 32 + quad * 8);
    }
    #pragma unroll
    for (int ms = 0; ms < 4; ++ms)
      #pragma unroll
      for (int ns = 0; ns < 2; ++ns)
        acc[ms][ns] = __builtin_amdgcn_mfma_f32_16x16x32_bf16(
            af[ms], bf[ns], acc[ms][ns], 0, 0, 0);
  }

  #pragma unroll
  for (int ns = 0; ns < 2; ++ns) {
    int p = p0 + wave * 32 + ns * 16 + lane15;
    if (p < HW) {
      #pragma unroll
      for (int ms = 0; ms < 4; ++ms) {
        int co0 = ms * 16 + quad * 4;
        float av[4] = {acc[ms][ns].x, acc[ms][ns].y, acc[ms][ns].z, acc[ms][ns].w};
        #pragma unroll
        for (int r = 0; r < 4; ++r) {
          size_t idx = (size_t)(gb * CO + co0 + r) * HW + p;
          out[idx] = av[r] + sh3[co0 + r] + x[idx];
        }
      }
    }
  }
}

// ---------------------------------------------------------------------------
extern "C" void kernel_launch(void* const* d_in, const int* in_sizes, int n_in,
                              void* d_out, int out_size, void* d_ws, size_t ws_size,
                              hipStream_t stream)
{
  (void)in_sizes; (void)n_in; (void)out_size;
  const float* x     = (const float*)d_in[0];
  const float* w_exp = (const float*)d_in[1];
  const float* g1 = (const float*)d_in[2];
  const float* b1 = (const float*)d_in[3];
  const float* m1 = (const float*)d_in[4];
  const float* v1 = (const float*)d_in[5];
  const float* w_dw = (const float*)d_in[6];
  const float* g2 = (const float*)d_in[7];
  const float* b2 = (const float*)d_in[8];
  const float* m2 = (const float*)d_in[9];
  const float* v2 = (const float*)d_in[10];
  const float* w_se1 = (const float*)d_in[11];
  const float* w_se2 = (const float*)d_in[12];
  const float* w_pw  = (const float*)d_in[13];
  const float* g3 = (const float*)d_in[14];
  const float* b3 = (const float*)d_in[15];
  const float* m3 = (const float*)d_in[16];
  const float* v3 = (const float*)d_in[17];

  const size_t perB = (size_t)XBATCH * 2 + (size_t)HID * HW * 2 * 2
                    + HID * 8 + 24576 * 2;
  const size_t fixed = 221184 * 2 + HID * 8 + CO * 8;
  int bc = Bn;
  while (bc > 1 && fixed + (size_t)bc * perB > ws_size) bc >>= 1;

  u16* wt = (u16*)d_ws;
  float* sc1 = (float*)(wt + 221184);
  float* sh1 = sc1 + HID;
  float* sc3 = sh1 + HID;
  float* sh3 = sc3 + CO;
  u16* xt = (u16*)(sh3 + CO);
  u16* h  = xt + (size_t)bc * XBATCH;
  u16* dd = h + (size_t)bc * HID * HW;
  u16* afold = dd + (size_t)bc * HID * HW;
  float* mean = (float*)(afold + (size_t)bc * 24576);
  float* sfac = mean + (size_t)bc * HID;

  k_prep_w<<<864, 256, 0, stream>>>(w_exp, wt);
  k_prep_bn<<<1, 384, 0, stream>>>(g1, b1, m1, v1, g3, b3, m3, v3,
                                   sc1, sh1, sc3, sh3);

  for (int b0 = 0; b0 < Bn; b0 += bc) {
    k_prep_x<<<dim3(58, bc), 256, 0, stream>>>(x, xt, b0);
    k_expand_mfma<<<dim3(3, 28, bc), 256, 0, stream>>>(xt, wt, sc1, sh1, h);
    k_dw<<<dim3(HID, bc), 256, 0, stream>>>(h, w_dw, g2, b2, m2, v2, dd, mean);
    k_se<<<bc, 256, 0, stream>>>(mean, w_se1, w_se2, sfac);
    k_prep_a<<<bc, 256, 0, stream>>>(w_pw, sfac, sc3, afold);
    k_pw_mfma<<<dim3(25, bc), 256, 0, stream>>>(dd, afold, sh3,
                                                x, (float*)d_out, b0);
  }
}